// Round 6
// baseline (640.469 us; speedup 1.0000x reference)
//
#include <hip/hip_runtime.h>

// entmax-1.5 attention, round 12: r7 (verified 108us) + double-buffered kv
// with ONE raw barrier per half (no vmcnt drains), Q direct-load, XCD swz.
// r11 post-mortem: global_load_lds wave-private DMA serialized (552us) —
// reverted to reg-staging where the COMPILER tracks vmcnt at the ds_write.
// Protocol per half h: [write regs(h+1)->kv[p^1]] [load regs(h+2)]
// [MFMA from kv[p]] [lgkmcnt(0); sched_barrier; s_barrier] p^=1.
// Barrier count ~33 (vs r7 ~66), and no barrier drains vmem.
// B=4 H=8 S=1024 D=128. Pre: K->bf16 [bh][key][d]; V->bf16 [bh][d][key].
// Main: 2048 blocks (32 bh x 64 q-tiles of 16 rows), 512 thr (8 waves).
// LDS = sc 32K + kv 2x16K = 65,536 B -> 2 blocks/CU.
// V halves 0/1 are loaded in phase-1's last two iterations, so their
// latency hides under the phase-2 solver; V0 is committed to LDS by the
// h=15 iteration itself.

#define S_ 1024
#define D_ 128
#define NEG_INF_F (-1.0e12f)
#define SCALE_F 0.08838834764831845f  // 1/sqrt(128)
#define NITER 14                      // dTau=6e-5 -> out err ~1e-3 << 0.0766
#define CCAP 512                      // cand cap (sc row = 512 f32)

typedef float f32x4 __attribute__((ext_vector_type(4)));
typedef short short8 __attribute__((ext_vector_type(8)));

__device__ __forceinline__ ushort f2bf(float x) {   // RNE f32 -> bf16
    unsigned u = __builtin_bit_cast(unsigned, x);
    u += 0x7FFFu + ((u >> 16) & 1u);
    return (ushort)(u >> 16);
}
__device__ __forceinline__ float bf2f(ushort h) {
    unsigned u = ((unsigned)h) << 16;
    return __builtin_bit_cast(float, u);
}
__device__ __forceinline__ short8 cvt8(float4 a, float4 b) {
    short8 r; ushort* p = (ushort*)&r;
    p[0] = f2bf(a.x); p[1] = f2bf(a.y); p[2] = f2bf(a.z); p[3] = f2bf(a.w);
    p[4] = f2bf(b.x); p[5] = f2bf(b.y); p[6] = f2bf(b.z); p[7] = f2bf(b.w);
    return r;
}

// one barrier: commit LDS ops, pin order, raw s_barrier (NO vmem drain)
#define BAR() do {                                              \
    asm volatile("s_waitcnt lgkmcnt(0)" ::: "memory");          \
    __builtin_amdgcn_sched_barrier(0);                          \
    __builtin_amdgcn_s_barrier();                               \
    asm volatile("" ::: "memory");                              \
} while (0)

// ---- fused pre-kernel: blocks 0..4095 K->bf16; 4096..5119 V->bf16-T ----
__global__ __launch_bounds__(256)
void pre_cvt(const float* __restrict__ K, const float* __restrict__ V,
             ushort* __restrict__ Kb, ushort* __restrict__ Vt)
{
    __shared__ __align__(16) ushort tileT[64][68];  // [d][key], pad->8B rows
    const int t = threadIdx.x;
    if (blockIdx.x < 4096) {                        // K convert (coalesced)
        int i = blockIdx.x * 256 + t;               // 1,048,576 float4s
        float4 v = ((const float4*)K)[i];
        ushort4 o;
        o.x = f2bf(v.x); o.y = f2bf(v.y); o.z = f2bf(v.z); o.w = f2bf(v.w);
        ((ushort4*)Kb)[i] = o;
        return;
    }
    // V transpose: 64x64 tile per block. 1024 blocks = 32 bh x 16 kt x 2 dh
    const int vb = blockIdx.x - 4096;
    const int bh = vb >> 5, r5 = vb & 31, kt = r5 >> 1, dh = r5 & 1;
    const float* src = V + ((size_t)(bh * S_ + kt * 64)) * D_ + dh * 64;
    #pragma unroll
    for (int i = 0; i < 4; ++i) {                   // 1024 float4 loads
        int idx = t + i * 256, r = idx >> 4, c = idx & 15;
        float4 vv = *(const float4*)(src + (size_t)r * D_ + c * 4);
        tileT[c * 4 + 0][r] = f2bf(vv.x);           // scatter-transpose
        tileT[c * 4 + 1][r] = f2bf(vv.y);
        tileT[c * 4 + 2][r] = f2bf(vv.z);
        tileT[c * 4 + 3][r] = f2bf(vv.w);
    }
    __syncthreads();
    ushort* dst = Vt + ((size_t)(bh * D_ + dh * 64)) * S_ + kt * 64;
    #pragma unroll
    for (int i = 0; i < 2; ++i) {                   // contiguous reads/stores
        int idx = t + i * 256, d = idx >> 3, jj = idx & 7;
        short8 val = *(const short8*)&tileT[d][jj * 8];
        *(short8*)(dst + (size_t)d * S_ + jj * 8) = val;
    }
}

// ---- main kernel --------------------------------------------------------
__global__ __launch_bounds__(512, 2)
void entmax_attn(const float* __restrict__ Q, const ushort* __restrict__ Kb,
                 const ushort* __restrict__ Vt, const int* __restrict__ M,
                 float* __restrict__ O)
{
    __shared__ __align__(16) ushort sc[16][1024];   // scores/P/cand overlay
    __shared__ __align__(16) ushort kv[2][128][64]; // double-buffered halves

    const int t = threadIdx.x;
    const int w = t >> 6, lane = t & 63, l = lane & 15, quad = lane >> 4;
    // XCD swizzle: 2048 % 8 == 0 -> bijective; each XCD gets 4 whole bh.
    const int swz = (blockIdx.x & 7) * 256 + (blockIdx.x >> 3);
    const int bh = swz >> 6, qt = swz & 63, b = bh >> 3;

    const ushort* kb_bh = Kb + (size_t)bh * (S_ * D_);
    const ushort* vt_bh = Vt + (size_t)bh * (D_ * S_);

    // staging: thread t owns rows sr0, sr0+64, chunk sch (16B each)
    const int sr0 = t >> 3, sch = t & 7, sr1 = sr0 + 64;
    const int wc0 = (sch ^ (sr0 & 7)) << 3;         // write col (swizzled)

    // fragment addresses: row n = w*16+l; chunks swizzled by l&7
    const int n = w * 16 + l;
    const int chA = (quad ^ (l & 7)) << 3;
    const int chB = ((4 + quad) ^ (l & 7)) << 3;

    // ---- Q fragments direct from global f32 (8 KB/block) ---------------
    short8 aq[4];                                   // A[m=l][k=ks*32+quad*8+e]
    {
        const float* qr = Q + ((size_t)(bh * S_ + qt * 16 + l)) * D_ + quad * 8;
        #pragma unroll
        for (int ks = 0; ks < 4; ++ks) {
            float4 qa = *(const float4*)(qr + ks * 32);
            float4 qb = *(const float4*)(qr + ks * 32 + 4);
            aq[ks] = cvt8(qa, qb);
        }
    }

    // ---- prologue: K half0 -> kv[0]; K half1 -> regs -------------------
    short8 s0, s1;
    {
        const ushort* g0 = kb_bh + (size_t)sr0 * D_ + sch * 8;      // half 0
        s0 = *(const short8*)g0;
        s1 = *(const short8*)(g0 + (size_t)64 * D_);
        *(short8*)&kv[0][sr0][wc0] = s0;
        *(short8*)&kv[0][sr1][wc0] = s1;
        const ushort* g1 = g0 + 64;                                 // half 1
        s0 = *(const short8*)g1;
        s1 = *(const short8*)(g1 + (size_t)64 * D_);
    }
    BAR();                                          // kv[0] visible

    // ---- phase 1: QK^T, 16 K-halves (kt=h>>1, dh=h&1), 1 bar/half ------
    int p = 0;
    f32x4 acc = {0.f, 0.f, 0.f, 0.f};
    #pragma unroll 1
    for (int h = 0; h < 16; ++h) {
        // 1) commit staged regs (K half h+1; V half0 when h==15) -> kv[p^1]
        *(short8*)&kv[p ^ 1][sr0][wc0] = s0;
        *(short8*)&kv[p ^ 1][sr1][wc0] = s1;
        // 2) issue next loads (K half h+2; V halves 0,1 at h=14,15)
        if (h < 14) {
            const int h2 = h + 2;
            const ushort* g = kb_bh + ((size_t)(h2 >> 1) * 128 + sr0) * D_
                              + (h2 & 1) * 64 + sch * 8;
            s0 = *(const short8*)g;
            s1 = *(const short8*)(g + (size_t)64 * D_);
        } else {
            const int vh = h - 14;                  // 0 or 1
            const ushort* g = vt_bh + (size_t)sr0 * S_ + vh * 64 + sch * 8;
            s0 = *(const short8*)g;
            s1 = *(const short8*)(g + (size_t)64 * S_);
        }
        // 3) MFMA from kv[p]
        short8 bk0 = *(const short8*)&kv[p][n][chA];
        short8 bk1 = *(const short8*)&kv[p][n][chB];
        const int dh = h & 1;
        if (dh == 0) { acc[0] = acc[1] = acc[2] = acc[3] = 0.f; }
        __builtin_amdgcn_s_setprio(1);
        acc = __builtin_amdgcn_mfma_f32_16x16x32_bf16(aq[dh * 2 + 0], bk0, acc, 0, 0, 0);
        acc = __builtin_amdgcn_mfma_f32_16x16x32_bf16(aq[dh * 2 + 1], bk1, acc, 0, 0, 0);
        __builtin_amdgcn_s_setprio(0);
        if (dh == 1) {                              // scaled scores -> sc
            const int coln = (h >> 1) * 16 + w * 2 + (l >> 3);
            #pragma unroll
            for (int r = 0; r < 4; ++r) {
                const int rr = quad * 4 + r;
                sc[rr][((coln ^ (rr & 7)) << 3) + (l & 7)] =
                    f2bf(acc[r] * SCALE_F);
            }
        }
        BAR();                                      // half h done; h+1 visible
        p ^= 1;
    }
    // now: p==0, kv[0] = V half0, regs = V half1, scores visible (last BAR)

    // ---- phase 2: regather + mask + max + normalize --------------------
    const int row = t >> 5, u = t & 31;             // 32 threads per row
    const int qg = qt * 16 + row;
    float x[32];
    #pragma unroll
    for (int c = 0; c < 4; ++c) {
        short8 v8 = *(const short8*)&sc[row][((c * 32 + u) ^ (row & 7)) << 3];
        #pragma unroll
        for (int e = 0; e < 8; ++e) x[c * 8 + e] = bf2f(((ushort*)&v8)[e]);
    }
    {   // mask: key = c*256 + u*8 + h*4 + e
        const int4* mrow = (const int4*)(M + ((size_t)b * S_ + qg) * S_);
        #pragma unroll
        for (int c = 0; c < 4; ++c) {
            #pragma unroll
            for (int h = 0; h < 2; ++h) {
                int4 mm = mrow[c * 64 + u * 2 + h];
                if (mm.x == 0) x[c * 8 + h * 4 + 0] = NEG_INF_F;
                if (mm.y == 0) x[c * 8 + h * 4 + 1] = NEG_INF_F;
                if (mm.z == 0) x[c * 8 + h * 4 + 2] = NEG_INF_F;
                if (mm.w == 0) x[c * 8 + h * 4 + 3] = NEG_INF_F;
            }
        }
    }
    float mx = -3.0e38f;
    #pragma unroll
    for (int j = 0; j < 32; ++j) mx = fmaxf(mx, x[j]);
    #pragma unroll
    for (int off = 1; off < 32; off <<= 1) mx = fmaxf(mx, __shfl_xor(mx, off));
    #pragma unroll
    for (int j = 0; j < 32; ++j) x[j] = (x[j] - mx) * 0.5f;   // x <= 0

    // ---- candidate compaction into own sc row (scores dead; lockstep) --
    float* cand = (float*)&sc[row][0];              // 512 f32 = the row
    const unsigned long long halfmask =
        (lane >= 32) ? 0xFFFFFFFF00000000ull : 0x00000000FFFFFFFFull;
    int cnt = 0;
    #pragma unroll
    for (int j = 0; j < 32; ++j) {
        const bool p2 = (x[j] > -1.0f);             // tau* >= -1
        unsigned long long bal = __ballot(p2) & halfmask;
        if (p2) {
            int pos = cnt + (int)__builtin_amdgcn_mbcnt_hi(
                (unsigned)(bal >> 32),
                __builtin_amdgcn_mbcnt_lo((unsigned)bal, 0));
            if (pos < CCAP) cand[pos] = x[j];
        }
        cnt += __popcll(bal);
    }

    // ---- tau bisection on f(tau)=sum max(0,x-tau)^2=1, root in [-1,0] --
    float tau;
    if (cnt <= CCAP) {                              // compact path (normal)
        float lo = -1.f, hi = 0.f;
        #pragma unroll 1
        for (int it = 0; it < NITER; ++it) {
            const float tm = 0.5f * (lo + hi);
            float f = 0.f;
            for (int j = u; j < cnt; j += 32) {
                float d = fmaxf(cand[j] - tm, 0.f);
                f = fmaf(d, d, f);
            }
            #pragma unroll
            for (int off = 1; off < 32; off <<= 1) f += __shfl_xor(f, off);
            const bool ge = (f >= 1.f);
            lo = ge ? tm : lo;
            hi = ge ? hi : tm;
        }
        tau = 0.5f * (lo + hi);
    } else {                                        // fallback: full solve
        float lo = -1.f, hi = 0.f;
        #pragma unroll 1
        for (int it = 0; it < NITER; ++it) {
            const float tm = 0.5f * (lo + hi);
            float f = 0.f;
            #pragma unroll
            for (int j = 0; j < 32; ++j) {
                float d = fmaxf(x[j] - tm, 0.f);
                f = fmaf(d, d, f);
            }
            #pragma unroll
            for (int off = 1; off < 32; off <<= 1) f += __shfl_xor(f, off);
            const bool ge = (f >= 1.f);
            lo = ge ? tm : lo;
            hi = ge ? hi : tm;
        }
        tau = 0.5f * (lo + hi);
    }

    // ---- y = max(0,x-tau)^2 back into sc (dense, swizzled) -------------
    #pragma unroll
    for (int c = 0; c < 4; ++c) {
        short8 v8;
        #pragma unroll
        for (int e = 0; e < 8; ++e) {
            float d = fmaxf(x[c * 8 + e] - tau, 0.f);
            ((ushort*)&v8)[e] = f2bf(d * d);
        }
        *(short8*)&sc[row][((c * 32 + u) ^ (row & 7)) << 3] = v8;
    }
    BAR();                                          // y visible (V0 already in)

    // ---- phase 3: O = P @ V^T, 16 V-halves (64 keys), 1 bar/half -------
    f32x4 oa = {0.f, 0.f, 0.f, 0.f};
    #pragma unroll 1
    for (int h2 = 0; h2 < 16; ++h2) {
        if (h2 < 15) {                              // commit V half h2+1
            *(short8*)&kv[p ^ 1][sr0][wc0] = s0;
            *(short8*)&kv[p ^ 1][sr1][wc0] = s1;
            if (h2 < 14) {                          // load V half h2+2
                const int vh = h2 + 2;
                const ushort* g = vt_bh + (size_t)sr0 * S_ + vh * 64 + sch * 8;
                s0 = *(const short8*)g;
                s1 = *(const short8*)(g + (size_t)64 * S_);
            }
        }
        short8 bv0 = *(const short8*)&kv[p][n][chA];
        short8 bv1 = *(const short8*)&kv[p][n][chB];
        short8 ap0 = *(const short8*)&sc[l][((h2 * 8 + quad) ^ (l & 7)) << 3];
        short8 ap1 = *(const short8*)&sc[l][((h2 * 8 + 4 + quad) ^ (l & 7)) << 3];
        __builtin_amdgcn_s_setprio(1);
        oa = __builtin_amdgcn_mfma_f32_16x16x32_bf16(ap0, bv0, oa, 0, 0, 0);
        oa = __builtin_amdgcn_mfma_f32_16x16x32_bf16(ap1, bv1, oa, 0, 0, 0);
        __builtin_amdgcn_s_setprio(0);
        if (h2 < 15) {
            BAR();
            p ^= 1;
        }
    }

    // ---- epilogue: C/D map (col=d-within-slice=l, row=q=quad*4+r) ------
    float* ob = O + ((size_t)bh * S_ + (size_t)qt * 16) * D_;
    #pragma unroll
    for (int r = 0; r < 4; ++r)
        ob[(size_t)(quad * 4 + r) * D_ + w * 16 + l] = oa[r];
}

extern "C" void kernel_launch(void* const* d_in, const int* in_sizes, int n_in,
                              void* d_out, int out_size, void* d_ws, size_t ws_size,
                              hipStream_t stream) {
    const float* q = (const float*)d_in[0];
    const float* k = (const float*)d_in[1];
    const float* v = (const float*)d_in[2];
    const int*   m = (const int*)d_in[3];
    float*       o = (float*)d_out;

    ushort* Kb = (ushort*)d_ws;                      // 8,388,608 B
    ushort* Vt = (ushort*)((char*)d_ws + 8388608);   // 8,388,608 B

    pre_cvt<<<5120, 256, 0, stream>>>(k, v, Kb, Vt);
    entmax_attn<<<2048, 512, 0, stream>>>(q, Kb, Vt, m, o);
}

// Round 7
// 193.144 us; speedup vs baseline: 3.3160x; 3.3160x over previous
//
#include <hip/hip_runtime.h>

// entmax-1.5 attention, round 13: REVERT to verified round-7 kernel
// (108 us entmax / 190 total) + ONE delta: XCD-aware block swizzle.
// r11/r12 post-mortem: the per-iteration asm-barrier template
// (lgkmcnt asm + sched_barrier(0) + raw s_barrier + "memory" clobbers)
// is a 4-6x pathology on this toolchain (552/580 us, MfmaUtil ~1.2%) --
// mechanism not isolated, template retired. __syncthreads-based staging
// is the verified-fast structure; this round re-establishes it.
// Delta: swz = (bid&7)*256 + bid>>3 (bijective, 2048%8==0). Each XCD gets
// 4 consecutive bh -> Kb+Vt 2 MB working set fits its private 4 MB L2
// (was 8-way duplicated); same-b mask rows collapse to 2 XCDs.
// B=4 H=8 S=1024 D=128. Pre: K->bf16 [bh][key][d]; V->bf16 [bh][d][key].
// Main: 2048 blocks (32 bh x 64 q-tiles of 16 rows), 512 thr (8 waves).
// LDS = sc 32K + kv 16K + q_s 4K = 53,248 B -> 3 blocks/CU (24 waves).
// Phase 1: QK^T in 64-wide d-halves (acc accumulates across halves).
// Phase 2: 32 thr/row regather+mask+max+normalize; ballot-compact {x > -1}
//          (tau* >= -1) into cand overlay on kv (CCAP=256); 14-iter
//          bisection; fallback full register solve if cnt > 256 (also
//          covers all-masked rows). y written back dense to sc.
// Phase 3: O = P @ V^T in 64-key halves, same swizzled fragments.

#define S_ 1024
#define D_ 128
#define NEG_INF_F (-1.0e12f)
#define SCALE_F 0.08838834764831845f  // 1/sqrt(128)
#define NITER 14                      // dTau=6e-5 -> out err ~1e-3 << 0.0766
#define CCAP 256                      // candidate cap per row (expected ~50)

typedef float f32x4 __attribute__((ext_vector_type(4)));
typedef short short8 __attribute__((ext_vector_type(8)));

__device__ __forceinline__ ushort f2bf(float x) {   // RNE f32 -> bf16
    unsigned u = __builtin_bit_cast(unsigned, x);
    u += 0x7FFFu + ((u >> 16) & 1u);
    return (ushort)(u >> 16);
}
__device__ __forceinline__ float bf2f(ushort h) {
    unsigned u = ((unsigned)h) << 16;
    return __builtin_bit_cast(float, u);
}

// ---- fused pre-kernel: blocks 0..4095 K->bf16; 4096..5119 V->bf16-T ----
// V transpose via write-side scatter (scalar LDS writes ~4-way) instead of
// read-side gather (was 16-way conflicted): store tileT[d][key] directly.
__global__ __launch_bounds__(256)
void pre_cvt(const float* __restrict__ K, const float* __restrict__ V,
             ushort* __restrict__ Kb, ushort* __restrict__ Vt)
{
    __shared__ __align__(16) ushort tileT[64][68];  // [d][key], pad->8B rows
    const int t = threadIdx.x;
    if (blockIdx.x < 4096) {                        // K convert (coalesced)
        int i = blockIdx.x * 256 + t;               // 1,048,576 float4s
        float4 v = ((const float4*)K)[i];
        ushort4 o;
        o.x = f2bf(v.x); o.y = f2bf(v.y); o.z = f2bf(v.z); o.w = f2bf(v.w);
        ((ushort4*)Kb)[i] = o;
        return;
    }
    // V transpose: 64x64 tile per block. 1024 blocks = 32 bh x 16 kt x 2 dh
    const int vb = blockIdx.x - 4096;
    const int bh = vb >> 5, r5 = vb & 31, kt = r5 >> 1, dh = r5 & 1;
    const float* src = V + ((size_t)(bh * S_ + kt * 64)) * D_ + dh * 64;
    #pragma unroll
    for (int i = 0; i < 4; ++i) {                   // 1024 float4 loads
        int idx = t + i * 256, r = idx >> 4, c = idx & 15;
        float4 vv = *(const float4*)(src + (size_t)r * D_ + c * 4);
        tileT[c * 4 + 0][r] = f2bf(vv.x);           // scatter-transpose
        tileT[c * 4 + 1][r] = f2bf(vv.y);
        tileT[c * 4 + 2][r] = f2bf(vv.z);
        tileT[c * 4 + 3][r] = f2bf(vv.w);
    }
    __syncthreads();
    ushort* dst = Vt + ((size_t)(bh * D_ + dh * 64)) * S_ + kt * 64;
    #pragma unroll
    for (int i = 0; i < 2; ++i) {                   // contiguous reads/stores
        int idx = t + i * 256, d = idx >> 3, jj = idx & 7;
        short8 val = *(const short8*)&tileT[d][jj * 8];
        *(short8*)(dst + (size_t)d * S_ + jj * 8) = val;
    }
}

// ---- main kernel --------------------------------------------------------
__global__ __launch_bounds__(512, 6)
void entmax_attn(const float* __restrict__ Q, const ushort* __restrict__ Kb,
                 const ushort* __restrict__ Vt, const int* __restrict__ M,
                 float* __restrict__ O)
{
    __shared__ __align__(16) ushort sc[16][1024];   // scores/P, swizzled
    __shared__ __align__(16) ushort kv[128][64];    // K/V^T half; cand overlay
    __shared__ __align__(16) ushort q_s[16][128];   // Q tile bf16, swizzled

    const int t = threadIdx.x;
    const int w = t >> 6, lane = t & 63, l = lane & 15, quad = lane >> 4;
    // XCD swizzle: 2048 % 8 == 0 -> bijective; XCD j gets logical ids
    // [j*256,(j+1)*256) = 4 whole bh -> Kb+Vt 2 MB L2-resident per XCD.
    const int swz = (blockIdx.x & 7) * 256 + (blockIdx.x >> 3);
    const int bh = swz >> 6, qt = swz & 63, b = bh >> 3;

    const ushort* kb_bh = Kb + (size_t)bh * S_ * D_;
    const ushort* vt_bh = Vt + (size_t)bh * D_ * S_;

    // staging: 128x64 half-tile = 1024 16B cells, 2 per thread
    const int sr0 = t >> 3, sch = t & 7, sr1 = sr0 + 64;
    ushort* kvw0 = &kv[sr0][(sch ^ (sr0 & 7)) << 3];
    ushort* kvw1 = &kv[sr1][(sch ^ (sr0 & 7)) << 3];   // sr1&7 == sr0&7

    // ---- stage Q tile (swizzled) + K half (kt0,d0..63); one barrier ----
    {
        const float4* qsrc = (const float4*)(Q + ((size_t)bh * S_ + (size_t)qt * 16) * D_);
        int r = t >> 5, c = t & 31;
        float4 v = qsrc[r * 32 + c];
        ushort4 o;
        o.x = f2bf(v.x); o.y = f2bf(v.y); o.z = f2bf(v.z); o.w = f2bf(v.w);
        *(ushort4*)&q_s[r][(((c >> 1) ^ (r & 7)) << 3) + ((c & 1) << 2)] = o;
    }
    short8 s0 = *(const short8*)(kb_bh + (size_t)sr0 * D_ + sch * 8);
    short8 s1 = *(const short8*)(kb_bh + (size_t)sr1 * D_ + sch * 8);
    *(short8*)kvw0 = s0;
    *(short8*)kvw1 = s1;
    __syncthreads();                                // q_s + K half 0 visible

    short8 aq[4];                                   // A[m=l][k=ks*32+quad*8+j]
    #pragma unroll
    for (int ks = 0; ks < 4; ++ks)
        aq[ks] = *(const short8*)&q_s[l][((ks * 4 + quad) ^ (l & 7)) << 3];

    // fragment pointers (rows n=d=w*16+l; chunks 0..7 swizzled by l&7)
    const int n = w * 16 + l;
    const ushort* kvA = &kv[n][(quad ^ (l & 7)) << 3];        // local ks 0
    const ushort* kvB = &kv[n][((4 + quad) ^ (l & 7)) << 3];  // local ks 1

    // ---- phase 1: QK^T, 8 key-tiles x 2 d-halves; acc spans halves -----
    #pragma unroll 1
    for (int kt = 0; kt < 8; ++kt) {
        f32x4 acc = {0.f, 0.f, 0.f, 0.f};
        #pragma unroll
        for (int kh = 0; kh < 2; ++kh) {
            const int h = kt * 2 + kh;
            if (h < 15) {                           // prefetch next half
                const int h2 = h + 1;
                const ushort* nb = kb_bh + (size_t)(h2 >> 1) * (128 * D_) + (h2 & 1) * 64;
                s0 = *(const short8*)(nb + (size_t)sr0 * D_ + sch * 8);
                s1 = *(const short8*)(nb + (size_t)sr1 * D_ + sch * 8);
            }
            __builtin_amdgcn_s_setprio(1);
            {
                short8 bk0 = *(const short8*)kvA;
                short8 bk1 = *(const short8*)kvB;
                acc = __builtin_amdgcn_mfma_f32_16x16x32_bf16(aq[kh * 2 + 0], bk0, acc, 0, 0, 0);
                acc = __builtin_amdgcn_mfma_f32_16x16x32_bf16(aq[kh * 2 + 1], bk1, acc, 0, 0, 0);
            }
            __builtin_amdgcn_s_setprio(0);
            if (kh == 1) {                          // scaled scores -> sc
                #pragma unroll
                for (int r = 0; r < 4; ++r) {
                    const int rr = quad * 4 + r, col = kt * 128 + n;
                    sc[rr][(((col >> 3) ^ (rr & 7)) << 3) + (col & 7)] =
                        f2bf(acc[r] * SCALE_F);
                }
            }
            __syncthreads();                        // kv reads done
            if (h < 15) {
                *(short8*)kvw0 = s0;
                *(short8*)kvw1 = s1;
                __syncthreads();                    // next half visible
            }
        }
    }

    // V^T half 0 into registers now (latency hides under solver)
    s0 = *(const short8*)(vt_bh + (size_t)sr0 * S_ + sch * 8);
    s1 = *(const short8*)(vt_bh + (size_t)sr1 * S_ + sch * 8);

    // ---- phase 2: regather + mask + max + normalize --------------------
    const int row = t >> 5, u = t & 31;             // 32 threads per row
    const int qg = qt * 16 + row;
    float x[32];
    #pragma unroll
    for (int c = 0; c < 4; ++c) {
        short8 v8 = *(const short8*)&sc[row][((c * 32 + u) ^ (row & 7)) << 3];
        #pragma unroll
        for (int e = 0; e < 8; ++e) x[c * 8 + e] = bf2f(((ushort*)&v8)[e]);
    }
    {   // mask: key = c*256 + u*8 + h*4 + e
        const int4* mrow = (const int4*)(M + ((size_t)b * S_ + qg) * S_);
        #pragma unroll
        for (int c = 0; c < 4; ++c) {
            #pragma unroll
            for (int h = 0; h < 2; ++h) {
                int4 mm = mrow[c * 64 + u * 2 + h];
                if (mm.x == 0) x[c * 8 + h * 4 + 0] = NEG_INF_F;
                if (mm.y == 0) x[c * 8 + h * 4 + 1] = NEG_INF_F;
                if (mm.z == 0) x[c * 8 + h * 4 + 2] = NEG_INF_F;
                if (mm.w == 0) x[c * 8 + h * 4 + 3] = NEG_INF_F;
            }
        }
    }
    float mx = -3.0e38f;
    #pragma unroll
    for (int j = 0; j < 32; ++j) mx = fmaxf(mx, x[j]);
    #pragma unroll
    for (int off = 1; off < 32; off <<= 1) mx = fmaxf(mx, __shfl_xor(mx, off));
    #pragma unroll
    for (int j = 0; j < 32; ++j) x[j] = (x[j] - mx) * 0.5f;   // x <= 0

    // ---- candidate compaction: exact set {x > -1} (tau* >= -1) ---------
    // cand overlays kv (dead until V store). 16 rows x 256 floats = 16 KB.
    float* cand = (float*)&kv[0][0];
    const unsigned long long halfmask =
        (lane >= 32) ? 0xFFFFFFFF00000000ull : 0x00000000FFFFFFFFull;
    int cnt = 0;
    #pragma unroll
    for (int j = 0; j < 32; ++j) {
        const bool p = (x[j] > -1.0f);
        unsigned long long bal = __ballot(p) & halfmask;
        if (p) {
            int pos = cnt + (int)__builtin_amdgcn_mbcnt_hi(
                (unsigned)(bal >> 32),
                __builtin_amdgcn_mbcnt_lo((unsigned)bal, 0));
            if (pos < CCAP) cand[row * CCAP + pos] = x[j];
        }
        cnt += __popcll(bal);
    }

    // ---- tau bisection on f(tau)=sum max(0,x-tau)^2=1, root in [-1,0] --
    float tau;
    if (cnt <= CCAP) {                              // compact path (normal)
        const float* crow = cand + row * CCAP;
        float lo = -1.f, hi = 0.f;
        #pragma unroll 1
        for (int it = 0; it < NITER; ++it) {
            const float tm = 0.5f * (lo + hi);
            float f = 0.f;
            for (int j = u; j < cnt; j += 32) {
                float d = fmaxf(crow[j] - tm, 0.f);
                f = fmaf(d, d, f);
            }
            #pragma unroll
            for (int off = 1; off < 32; off <<= 1) f += __shfl_xor(f, off);
            const bool ge = (f >= 1.f);
            lo = ge ? tm : lo;
            hi = ge ? hi : tm;
        }
        tau = 0.5f * (lo + hi);
    } else {                                        // fallback: full solve
        float lo = -1.f, hi = 0.f;
        #pragma unroll 1
        for (int it = 0; it < NITER; ++it) {
            const float tm = 0.5f * (lo + hi);
            float f = 0.f;
            #pragma unroll
            for (int j = 0; j < 32; ++j) {
                float d = fmaxf(x[j] - tm, 0.f);
                f = fmaf(d, d, f);
            }
            #pragma unroll
            for (int off = 1; off < 32; off <<= 1) f += __shfl_xor(f, off);
            const bool ge = (f >= 1.f);
            lo = ge ? tm : lo;
            hi = ge ? hi : tm;
        }
        tau = 0.5f * (lo + hi);
    }

    // ---- y = max(0,x-tau)^2 back into sc (dense, swizzled) -------------
    #pragma unroll
    for (int c = 0; c < 4; ++c) {
        short8 v8;
        #pragma unroll
        for (int e = 0; e < 8; ++e) {
            float d = fmaxf(x[c * 8 + e] - tau, 0.f);
            ((ushort*)&v8)[e] = f2bf(d * d);
        }
        *(short8*)&sc[row][((c * 32 + u) ^ (row & 7)) << 3] = v8;
    }
    __syncthreads();                                // cand reads + y done
    *(short8*)kvw0 = s0;                            // V^T half 0 -> kv
    *(short8*)kvw1 = s1;
    __syncthreads();                                // V half 0 + y visible

    // ---- phase 3: O = P @ V, 16 key-halves; wave w owns d w*16..+15 ----
    f32x4 oa = {0.f, 0.f, 0.f, 0.f};
    #pragma unroll 1
    for (int vh = 0; vh < 16; ++vh) {
        if (vh < 15) {                              // prefetch next half
            const ushort* nb = vt_bh + (size_t)(vh + 1) * 64;
            s0 = *(const short8*)(nb + (size_t)sr0 * S_ + sch * 8);
            s1 = *(const short8*)(nb + (size_t)sr1 * S_ + sch * 8);
        }
        __builtin_amdgcn_s_setprio(1);
        {
            short8 ap0 = *(const short8*)&sc[l][((vh * 8 + quad) ^ (l & 7)) << 3];
            short8 ap1 = *(const short8*)&sc[l][((vh * 8 + 4 + quad) ^ (l & 7)) << 3];
            short8 bv0 = *(const short8*)kvA;
            short8 bv1 = *(const short8*)kvB;
            oa = __builtin_amdgcn_mfma_f32_16x16x32_bf16(ap0, bv0, oa, 0, 0, 0);
            oa = __builtin_amdgcn_mfma_f32_16x16x32_bf16(ap1, bv1, oa, 0, 0, 0);
        }
        __builtin_amdgcn_s_setprio(0);
        __syncthreads();                            // kv reads done
        if (vh < 15) {
            *(short8*)kvw0 = s0;
            *(short8*)kvw1 = s1;
            __syncthreads();                        // next half visible
        }
    }

    // ---- epilogue: C/D map (col=d-within-slice=l, row=q=quad*4+r) ------
    float* ob = O + ((size_t)bh * S_ + (size_t)qt * 16) * D_;
    #pragma unroll
    for (int r = 0; r < 4; ++r)
        ob[(size_t)(quad * 4 + r) * D_ + w * 16 + l] = oa[r];
}

extern "C" void kernel_launch(void* const* d_in, const int* in_sizes, int n_in,
                              void* d_out, int out_size, void* d_ws, size_t ws_size,
                              hipStream_t stream) {
    const float* q = (const float*)d_in[0];
    const float* k = (const float*)d_in[1];
    const float* v = (const float*)d_in[2];
    const int*   m = (const int*)d_in[3];
    float*       o = (float*)d_out;

    ushort* Kb = (ushort*)d_ws;                      // 8,388,608 B
    ushort* Vt = (ushort*)((char*)d_ws + 8388608);   // 8,388,608 B

    pre_cvt<<<5120, 256, 0, stream>>>(k, v, Kb, Vt);
    entmax_attn<<<2048, 512, 0, stream>>>(q, Kb, Vt, m, o);
}

// Round 8
// 191.341 us; speedup vs baseline: 3.3473x; 1.0094x over previous
//
#include <hip/hip_runtime.h>

// entmax-1.5 attention, round 14: verified r13 base (112us entmax) + ONE
// delta: BIT-PACKED MASK. The int32 mask was 128 MB of logical reads
// (16 rows x 4 KB x 2048 blocks), thrashing XCD-L2 (4.2 MB/b working set)
// and stalling phase 2 with 8x int4 dependent loads per thread right
// after the barrier. Pre-kernel packs to 1 bit/key in thread order:
// Mp[b][qrow] = 128 B; uint32 word u = {bytes c=0..3}, bit j = key
// c*256+u*8+j. Main kernel: ONE uint32 per thread, loaded at kernel
// start (latency hides under all of phase 1); phase 2 has zero global
// loads. Total packed mask = 512 KB -> L2-resident on every XCD.
// Everything else byte-identical to r13 (53,248 B LDS, 3 blocks/CU,
// XCD swizzle, candidate-compact solver, 2-barrier-per-half staging).

#define S_ 1024
#define D_ 128
#define NEG_INF_F (-1.0e12f)
#define SCALE_F 0.08838834764831845f  // 1/sqrt(128)
#define NITER 14                      // dTau=6e-5 -> out err ~1e-3 << 0.0766
#define CCAP 256                      // candidate cap per row (expected ~50)

typedef float f32x4 __attribute__((ext_vector_type(4)));
typedef short short8 __attribute__((ext_vector_type(8)));

__device__ __forceinline__ ushort f2bf(float x) {   // RNE f32 -> bf16
    unsigned u = __builtin_bit_cast(unsigned, x);
    u += 0x7FFFu + ((u >> 16) & 1u);
    return (ushort)(u >> 16);
}
__device__ __forceinline__ float bf2f(ushort h) {
    unsigned u = ((unsigned)h) << 16;
    return __builtin_bit_cast(float, u);
}

// ---- fused pre-kernel ---------------------------------------------------
// blocks 0..4095: K->bf16. 4096..5119: V->bf16-T. 5120..5631: mask pack.
__global__ __launch_bounds__(256)
void pre_cvt(const float* __restrict__ K, const float* __restrict__ V,
             const int* __restrict__ M,
             ushort* __restrict__ Kb, ushort* __restrict__ Vt,
             unsigned* __restrict__ Mp)
{
    __shared__ __align__(16) ushort tileT[64][68];  // [d][key], pad->8B rows
    const int t = threadIdx.x;
    if (blockIdx.x < 4096) {                        // K convert (coalesced)
        int i = blockIdx.x * 256 + t;               // 1,048,576 float4s
        float4 v = ((const float4*)K)[i];
        ushort4 o;
        o.x = f2bf(v.x); o.y = f2bf(v.y); o.z = f2bf(v.z); o.w = f2bf(v.w);
        ((ushort4*)Kb)[i] = o;
        return;
    }
    if (blockIdx.x >= 5120) {                       // mask pack (1 bit/key)
        const int g = (blockIdx.x - 5120) * 256 + t;    // 0..131071
        const int mrow = g >> 5, u = g & 31;            // row 0..4095
        const int* src = M + (size_t)mrow * 1024 + u * 8;
        unsigned out = 0;
        #pragma unroll
        for (int c = 0; c < 4; ++c) {               // byte c: keys c*256+u*8..+7
            int4 a = *(const int4*)(src + c * 256);
            int4 b4 = *(const int4*)(src + c * 256 + 4);
            unsigned byte =
                (unsigned)(a.x != 0)       | ((unsigned)(a.y != 0) << 1) |
                ((unsigned)(a.z != 0) << 2)| ((unsigned)(a.w != 0) << 3) |
                ((unsigned)(b4.x != 0) << 4)| ((unsigned)(b4.y != 0) << 5) |
                ((unsigned)(b4.z != 0) << 6)| ((unsigned)(b4.w != 0) << 7);
            out |= byte << (c * 8);
        }
        Mp[(size_t)mrow * 32 + u] = out;
        return;
    }
    // V transpose: 64x64 tile per block. 1024 blocks = 32 bh x 16 kt x 2 dh
    const int vb = blockIdx.x - 4096;
    const int bh = vb >> 5, r5 = vb & 31, kt = r5 >> 1, dh = r5 & 1;
    const float* src = V + ((size_t)(bh * S_ + kt * 64)) * D_ + dh * 64;
    #pragma unroll
    for (int i = 0; i < 4; ++i) {                   // 1024 float4 loads
        int idx = t + i * 256, r = idx >> 4, c = idx & 15;
        float4 vv = *(const float4*)(src + (size_t)r * D_ + c * 4);
        tileT[c * 4 + 0][r] = f2bf(vv.x);           // scatter-transpose
        tileT[c * 4 + 1][r] = f2bf(vv.y);
        tileT[c * 4 + 2][r] = f2bf(vv.z);
        tileT[c * 4 + 3][r] = f2bf(vv.w);
    }
    __syncthreads();
    ushort* dst = Vt + ((size_t)(bh * D_ + dh * 64)) * S_ + kt * 64;
    #pragma unroll
    for (int i = 0; i < 2; ++i) {                   // contiguous reads/stores
        int idx = t + i * 256, d = idx >> 3, jj = idx & 7;
        short8 val = *(const short8*)&tileT[d][jj * 8];
        *(short8*)(dst + (size_t)d * S_ + jj * 8) = val;
    }
}

// ---- main kernel --------------------------------------------------------
__global__ __launch_bounds__(512, 6)
void entmax_attn(const float* __restrict__ Q, const ushort* __restrict__ Kb,
                 const ushort* __restrict__ Vt, const unsigned* __restrict__ Mp,
                 float* __restrict__ O)
{
    __shared__ __align__(16) ushort sc[16][1024];   // scores/P, swizzled
    __shared__ __align__(16) ushort kv[128][64];    // K/V^T half; cand overlay
    __shared__ __align__(16) ushort q_s[16][128];   // Q tile bf16, swizzled

    const int t = threadIdx.x;
    const int w = t >> 6, lane = t & 63, l = lane & 15, quad = lane >> 4;
    // XCD swizzle: 2048 % 8 == 0 -> bijective; XCD j gets logical ids
    // [j*256,(j+1)*256) = 4 whole bh -> Kb+Vt 2 MB L2-resident per XCD.
    const int swz = (blockIdx.x & 7) * 256 + (blockIdx.x >> 3);
    const int bh = swz >> 6, qt = swz & 63, b = bh >> 3;

    const ushort* kb_bh = Kb + (size_t)bh * S_ * D_;
    const ushort* vt_bh = Vt + (size_t)bh * D_ * S_;

    // ---- packed mask word: ONE dword/thread, issued NOW so its latency
    // hides under all of phase 1 (phase 2 has zero global loads) ---------
    const int row = t >> 5, u = t & 31;             // phase-2 coords
    const int qg = qt * 16 + row;
    const unsigned mw = Mp[(size_t)(b * S_ + qg) * 32 + u];

    // staging: 128x64 half-tile = 1024 16B cells, 2 per thread
    const int sr0 = t >> 3, sch = t & 7, sr1 = sr0 + 64;
    ushort* kvw0 = &kv[sr0][(sch ^ (sr0 & 7)) << 3];
    ushort* kvw1 = &kv[sr1][(sch ^ (sr0 & 7)) << 3];   // sr1&7 == sr0&7

    // ---- stage Q tile (swizzled) + K half (kt0,d0..63); one barrier ----
    {
        const float4* qsrc = (const float4*)(Q + ((size_t)bh * S_ + (size_t)qt * 16) * D_);
        int r = t >> 5, c = t & 31;
        float4 v = qsrc[r * 32 + c];
        ushort4 o;
        o.x = f2bf(v.x); o.y = f2bf(v.y); o.z = f2bf(v.z); o.w = f2bf(v.w);
        *(ushort4*)&q_s[r][(((c >> 1) ^ (r & 7)) << 3) + ((c & 1) << 2)] = o;
    }
    short8 s0 = *(const short8*)(kb_bh + (size_t)sr0 * D_ + sch * 8);
    short8 s1 = *(const short8*)(kb_bh + (size_t)sr1 * D_ + sch * 8);
    *(short8*)kvw0 = s0;
    *(short8*)kvw1 = s1;
    __syncthreads();                                // q_s + K half 0 visible

    short8 aq[4];                                   // A[m=l][k=ks*32+quad*8+j]
    #pragma unroll
    for (int ks = 0; ks < 4; ++ks)
        aq[ks] = *(const short8*)&q_s[l][((ks * 4 + quad) ^ (l & 7)) << 3];

    // fragment pointers (rows n=d=w*16+l; chunks 0..7 swizzled by l&7)
    const int n = w * 16 + l;
    const ushort* kvA = &kv[n][(quad ^ (l & 7)) << 3];        // local ks 0
    const ushort* kvB = &kv[n][((4 + quad) ^ (l & 7)) << 3];  // local ks 1

    // ---- phase 1: QK^T, 8 key-tiles x 2 d-halves; acc spans halves -----
    #pragma unroll 1
    for (int kt = 0; kt < 8; ++kt) {
        f32x4 acc = {0.f, 0.f, 0.f, 0.f};
        #pragma unroll
        for (int kh = 0; kh < 2; ++kh) {
            const int h = kt * 2 + kh;
            if (h < 15) {                           // prefetch next half
                const int h2 = h + 1;
                const ushort* nb = kb_bh + (size_t)(h2 >> 1) * (128 * D_) + (h2 & 1) * 64;
                s0 = *(const short8*)(nb + (size_t)sr0 * D_ + sch * 8);
                s1 = *(const short8*)(nb + (size_t)sr1 * D_ + sch * 8);
            }
            __builtin_amdgcn_s_setprio(1);
            {
                short8 bk0 = *(const short8*)kvA;
                short8 bk1 = *(const short8*)kvB;
                acc = __builtin_amdgcn_mfma_f32_16x16x32_bf16(aq[kh * 2 + 0], bk0, acc, 0, 0, 0);
                acc = __builtin_amdgcn_mfma_f32_16x16x32_bf16(aq[kh * 2 + 1], bk1, acc, 0, 0, 0);
            }
            __builtin_amdgcn_s_setprio(0);
            if (kh == 1) {                          // scaled scores -> sc
                #pragma unroll
                for (int r = 0; r < 4; ++r) {
                    const int rr = quad * 4 + r, col = kt * 128 + n;
                    sc[rr][(((col >> 3) ^ (rr & 7)) << 3) + (col & 7)] =
                        f2bf(acc[r] * SCALE_F);
                }
            }
            __syncthreads();                        // kv reads done
            if (h < 15) {
                *(short8*)kvw0 = s0;
                *(short8*)kvw1 = s1;
                __syncthreads();                    // next half visible
            }
        }
    }

    // V^T half 0 into registers now (latency hides under solver)
    s0 = *(const short8*)(vt_bh + (size_t)sr0 * S_ + sch * 8);
    s1 = *(const short8*)(vt_bh + (size_t)sr1 * S_ + sch * 8);

    // ---- phase 2: regather + mask(packed) + max + normalize ------------
    float x[32];
    #pragma unroll
    for (int c = 0; c < 4; ++c) {
        short8 v8 = *(const short8*)&sc[row][((c * 32 + u) ^ (row & 7)) << 3];
        #pragma unroll
        for (int e = 0; e < 8; ++e) x[c * 8 + e] = bf2f(((ushort*)&v8)[e]);
    }
    #pragma unroll
    for (int c = 0; c < 4; ++c) {                   // bit j of byte c
        #pragma unroll
        for (int e = 0; e < 8; ++e)
            if (!((mw >> (c * 8 + e)) & 1u)) x[c * 8 + e] = NEG_INF_F;
    }
    float mx = -3.0e38f;
    #pragma unroll
    for (int j = 0; j < 32; ++j) mx = fmaxf(mx, x[j]);
    #pragma unroll
    for (int off = 1; off < 32; off <<= 1) mx = fmaxf(mx, __shfl_xor(mx, off));
    #pragma unroll
    for (int j = 0; j < 32; ++j) x[j] = (x[j] - mx) * 0.5f;   // x <= 0

    // ---- candidate compaction: exact set {x > -1} (tau* >= -1) ---------
    // cand overlays kv (dead until V store). 16 rows x 256 floats = 16 KB.
    float* cand = (float*)&kv[0][0];
    const unsigned long long halfmask =
        (lane >= 32) ? 0xFFFFFFFF00000000ull : 0x00000000FFFFFFFFull;
    int cnt = 0;
    #pragma unroll
    for (int j = 0; j < 32; ++j) {
        const bool p = (x[j] > -1.0f);
        unsigned long long bal = __ballot(p) & halfmask;
        if (p) {
            int pos = cnt + (int)__builtin_amdgcn_mbcnt_hi(
                (unsigned)(bal >> 32),
                __builtin_amdgcn_mbcnt_lo((unsigned)bal, 0));
            if (pos < CCAP) cand[row * CCAP + pos] = x[j];
        }
        cnt += __popcll(bal);
    }

    // ---- tau bisection on f(tau)=sum max(0,x-tau)^2=1, root in [-1,0] --
    float tau;
    if (cnt <= CCAP) {                              // compact path (normal)
        const float* crow = cand + row * CCAP;
        float lo = -1.f, hi = 0.f;
        #pragma unroll 1
        for (int it = 0; it < NITER; ++it) {
            const float tm = 0.5f * (lo + hi);
            float f = 0.f;
            for (int j = u; j < cnt; j += 32) {
                float d = fmaxf(crow[j] - tm, 0.f);
                f = fmaf(d, d, f);
            }
            #pragma unroll
            for (int off = 1; off < 32; off <<= 1) f += __shfl_xor(f, off);
            const bool ge = (f >= 1.f);
            lo = ge ? tm : lo;
            hi = ge ? hi : tm;
        }
        tau = 0.5f * (lo + hi);
    } else {                                        // fallback: full solve
        float lo = -1.f, hi = 0.f;
        #pragma unroll 1
        for (int it = 0; it < NITER; ++it) {
            const float tm = 0.5f * (lo + hi);
            float f = 0.f;
            #pragma unroll
            for (int j = 0; j < 32; ++j) {
                float d = fmaxf(x[j] - tm, 0.f);
                f = fmaf(d, d, f);
            }
            #pragma unroll
            for (int off = 1; off < 32; off <<= 1) f += __shfl_xor(f, off);
            const bool ge = (f >= 1.f);
            lo = ge ? tm : lo;
            hi = ge ? hi : tm;
        }
        tau = 0.5f * (lo + hi);
    }

    // ---- y = max(0,x-tau)^2 back into sc (dense, swizzled) -------------
    #pragma unroll
    for (int c = 0; c < 4; ++c) {
        short8 v8;
        #pragma unroll
        for (int e = 0; e < 8; ++e) {
            float d = fmaxf(x[c * 8 + e] - tau, 0.f);
            ((ushort*)&v8)[e] = f2bf(d * d);
        }
        *(short8*)&sc[row][((c * 32 + u) ^ (row & 7)) << 3] = v8;
    }
    __syncthreads();                                // cand reads + y done
    *(short8*)kvw0 = s0;                            // V^T half 0 -> kv
    *(short8*)kvw1 = s1;
    __syncthreads();                                // V half 0 + y visible

    // ---- phase 3: O = P @ V, 16 key-halves; wave w owns d w*16..+15 ----
    f32x4 oa = {0.f, 0.f, 0.f, 0.f};
    #pragma unroll 1
    for (int vh = 0; vh < 16; ++vh) {
        if (vh < 15) {                              // prefetch next half
            const ushort* nb = vt_bh + (size_t)(vh + 1) * 64;
            s0 = *(const short8*)(nb + (size_t)sr0 * S_ + sch * 8);
            s1 = *(const short8*)(nb + (size_t)sr1 * S_ + sch * 8);
        }
        __builtin_amdgcn_s_setprio(1);
        {
            short8 ap0 = *(const short8*)&sc[l][((vh * 8 + quad) ^ (l & 7)) << 3];
            short8 ap1 = *(const short8*)&sc[l][((vh * 8 + 4 + quad) ^ (l & 7)) << 3];
            short8 bv0 = *(const short8*)kvA;
            short8 bv1 = *(const short8*)kvB;
            oa = __builtin_amdgcn_mfma_f32_16x16x32_bf16(ap0, bv0, oa, 0, 0, 0);
            oa = __builtin_amdgcn_mfma_f32_16x16x32_bf16(ap1, bv1, oa, 0, 0, 0);
        }
        __builtin_amdgcn_s_setprio(0);
        __syncthreads();                            // kv reads done
        if (vh < 15) {
            *(short8*)kvw0 = s0;
            *(short8*)kvw1 = s1;
            __syncthreads();                        // next half visible
        }
    }

    // ---- epilogue: C/D map (col=d-within-slice=l, row=q=quad*4+r) ------
    float* ob = O + ((size_t)bh * S_ + (size_t)qt * 16) * D_;
    #pragma unroll
    for (int r = 0; r < 4; ++r)
        ob[(size_t)(quad * 4 + r) * D_ + w * 16 + l] = oa[r];
}

extern "C" void kernel_launch(void* const* d_in, const int* in_sizes, int n_in,
                              void* d_out, int out_size, void* d_ws, size_t ws_size,
                              hipStream_t stream) {
    const float* q = (const float*)d_in[0];
    const float* k = (const float*)d_in[1];
    const float* v = (const float*)d_in[2];
    const int*   m = (const int*)d_in[3];
    float*       o = (float*)d_out;

    ushort*   Kb = (ushort*)d_ws;                         // 8,388,608 B
    ushort*   Vt = (ushort*)((char*)d_ws + 8388608);      // 8,388,608 B
    unsigned* Mp = (unsigned*)((char*)d_ws + 16777216);   //   524,288 B

    pre_cvt<<<5632, 256, 0, stream>>>(k, v, m, Kb, Vt, Mp);
    entmax_attn<<<2048, 512, 0, stream>>>(q, Kb, Vt, Mp, o);
}